// Round 12
// baseline (153.856 us; speedup 1.0000x reference)
//
#include <hip/hip_runtime.h>

// YOLO v1-style loss, forward only.
// prediction: [32768, 7, 7, 12] f32   (B=2 boxes * 5 + C=2 classes)
// target:     [32768, 7, 7, 7]  f32   (x,y,w,h,obj, c0,c1)
// output:     scalar f32
//
// Round-12: CPT 4 -> 8. 38 independent global_load_dwordx4 per thread
// (24 pred + 14 targ, both float4-aligned: 8*12=96 floats, 8*7=56 floats),
// asm keep-alive fence keeps them all in flight. 128-thread blocks x 1568.
// launch_bounds(128,2) caps VGPR at 256 (no spill; data regs = 152).
// Per-wave partial -> plain store; no LDS staging, no atomics.

constexpr int S = 7;
constexpr int CELLS = 32768 * S * S;          // 1,605,632
constexpr int CPT = 8;                        // cells per thread
constexpr int TPB = 128;                      // threads per block (2 waves)
constexpr int NTHREADS = CELLS / CPT;         // 200,704
constexpr int NBLK = NTHREADS / TPB;          // 1568
constexpr int NWAVES = NTHREADS / 64;         // 3136
constexpr float LAMBDA_COORD = 5.0f;
constexpr float LAMBDA_NOOBJ = 0.5f;
constexpr float INV_S = 1.0f / 7.0f;

__device__ __forceinline__ float cell_loss(const float* p, const float* t,
                                           float fcol, float frow) {
    float x0 = p[0], y0 = p[1], w0 = p[2], h0 = p[3], c0 = p[4];
    float x1 = p[5], y1 = p[6], w1 = p[7], h1 = p[8], c1 = p[9];
    float q0 = p[10], q1 = p[11];
    float tx = t[0], ty = t[1], tw = t[2], th = t[3], tp = t[4];
    float s0 = t[5], s1 = t[6];

    // target corners + area
    float tcx = (tx + fcol) * INV_S, tcy = (ty + frow) * INV_S;
    float tX1 = tcx - tw * 0.5f, tY1 = tcy - th * 0.5f;
    float tX2 = tcx + tw * 0.5f, tY2 = tcy + th * 0.5f;
    float ta = fabsf((tX2 - tX1) * (tY2 - tY1));

    // box 0
    float cx0 = (x0 + fcol) * INV_S, cy0 = (y0 + frow) * INV_S;
    float aX1 = cx0 - w0 * 0.5f, aY1 = cy0 - h0 * 0.5f;
    float aX2 = cx0 + w0 * 0.5f, aY2 = cy0 + h0 * 0.5f;
    float inter0 = fmaxf(fminf(aX2, tX2) - fmaxf(aX1, tX1), 0.0f) *
                   fmaxf(fminf(aY2, tY2) - fmaxf(aY1, tY1), 0.0f);
    float ar0 = fabsf((aX2 - aX1) * (aY2 - aY1));
    float u0 = ar0 + ta - inter0 + 1e-8f;      // > 0 always

    // box 1
    float cx1 = (x1 + fcol) * INV_S, cy1 = (y1 + frow) * INV_S;
    float bX1 = cx1 - w1 * 0.5f, bY1 = cy1 - h1 * 0.5f;
    float bX2 = cx1 + w1 * 0.5f, bY2 = cy1 + h1 * 0.5f;
    float inter1 = fmaxf(fminf(bX2, tX2) - fmaxf(bX1, tX1), 0.0f) *
                   fmaxf(fminf(bY2, tY2) - fmaxf(bY1, tY1), 0.0f);
    float ar1 = fabsf((bX2 - bX1) * (bY2 - bY1));
    float u1 = ar1 + ta - inter1 + 1e-8f;

    // argmax(iou): box1 iff iou1 > iou0  <=>  inter1*u0 > inter0*u1  (u > 0)
    bool sel1 = inter1 * u0 > inter0 * u1;
    float px = sel1 ? x1 : x0;
    float py = sel1 ? y1 : y0;
    float pw = sel1 ? w1 : w0;
    float ph = sel1 ? h1 : h0;
    float pp = sel1 ? c1 : c0;

    float obj = (tp > 0.0f) ? 1.0f : 0.0f;
    float noobj = 1.0f - obj;

    float dx = px - tx, dy = py - ty;
    float centre = dx * dx + dy * dy;

    float sgnw = (pw > 0.0f) ? 1.0f : ((pw < 0.0f) ? -1.0f : 0.0f);
    float sgnh = (ph > 0.0f) ? 1.0f : ((ph < 0.0f) ? -1.0f : 0.0f);
    float dw = sgnw * sqrtf(fabsf(pw) + 1e-6f) - sqrtf(tw);
    float dh = sgnh * sqrtf(fabsf(ph) + 1e-6f) - sqrtf(th);
    float dim = dw * dw + dh * dh;

    float dconf = pp - tp;
    float n0 = c0 - tp, n1 = c1 - tp;
    float dc0 = q0 - s0, dc1 = q1 - s1;

    return obj * (LAMBDA_COORD * (centre + dim) + dconf * dconf + dc0 * dc0 + dc1 * dc1)
         + noobj * LAMBDA_NOOBJ * (n0 * n0 + n1 * n1);
}

__global__ __launch_bounds__(TPB, 2)
void yolo_loss_kernel(const float* __restrict__ pred,
                      const float* __restrict__ targ,
                      double* __restrict__ ws) {
    int tid = blockIdx.x * blockDim.x + threadIdx.x;
    int base = tid * CPT;

    float4 pv[24];                 // 8 cells * 12 floats = 24 float4
    float4 tv[14];                 // 8 cells * 7  floats = 14 float4
    const float4* p4 = reinterpret_cast<const float4*>(pred + (size_t)base * 12);
    const float4* t4 = reinterpret_cast<const float4*>(targ + (size_t)base * 7);
    #pragma unroll
    for (int k = 0; k < 24; ++k) pv[k] = p4[k];
    #pragma unroll
    for (int k = 0; k < 14; ++k) tv[k] = t4[k];

    // MLP fence: force all 38 global_load_dwordx4 to issue before any compute.
    #pragma unroll
    for (int k = 0; k < 24; ++k)
        asm volatile("" : "+v"(pv[k].x), "+v"(pv[k].y), "+v"(pv[k].z), "+v"(pv[k].w));
    #pragma unroll
    for (int k = 0; k < 14; ++k)
        asm volatile("" : "+v"(tv[k].x), "+v"(tv[k].y), "+v"(tv[k].z), "+v"(tv[k].w));

    const float* pf = reinterpret_cast<const float*>(pv);
    const float* tf = reinterpret_cast<const float*>(tv);

    int j = base % S;
    int i = (base / S) % S;

    float acc = 0.0f;
    #pragma unroll
    for (int k = 0; k < CPT; ++k) {
        acc += cell_loss(pf + k * 12, tf + k * 7, (float)j, (float)i);
        if (++j == S) { j = 0; if (++i == S) i = 0; }
    }

    // per-wave reduction in double -> one plain 8B store per wave
    double v = (double)acc;
    #pragma unroll
    for (int off = 32; off > 0; off >>= 1)
        v += __shfl_down(v, off, 64);

    if ((threadIdx.x & 63) == 0)
        ws[tid >> 6] = v;                      // global wave index
}

__global__ __launch_bounds__(256)
void reduce_kernel(const double* __restrict__ ws, float* __restrict__ out) {
    int t = threadIdx.x;
    double s = 0.0;
    for (int idx = t; idx < NWAVES; idx += 256) s += ws[idx];

    #pragma unroll
    for (int off = 32; off > 0; off >>= 1)
        s += __shfl_down(s, off, 64);

    __shared__ double sm[4];
    int lane = t & 63, wid = t >> 6;
    if (lane == 0) sm[wid] = s;
    __syncthreads();
    if (t == 0) out[0] = (float)(sm[0] + sm[1] + sm[2] + sm[3]);
}

extern "C" void kernel_launch(void* const* d_in, const int* in_sizes, int n_in,
                              void* d_out, int out_size, void* d_ws, size_t ws_size,
                              hipStream_t stream) {
    const float* pred = (const float*)d_in[0];
    const float* targ = (const float*)d_in[1];
    float* out = (float*)d_out;
    double* ws = (double*)d_ws;

    yolo_loss_kernel<<<NBLK, TPB, 0, stream>>>(pred, targ, ws);
    reduce_kernel<<<1, 256, 0, stream>>>(ws, out);
}

// Round 13
// 151.076 us; speedup vs baseline: 1.0184x; 1.0184x over previous
//
#include <hip/hip_runtime.h>

// YOLO v1-style loss, forward only.
// prediction: [32768, 7, 7, 12] f32   (B=2 boxes * 5 + C=2 classes)
// target:     [32768, 7, 7, 7]  f32   (x,y,w,h,obj, c0,c1)
// output:     scalar f32
//
// Round-13: register double-buffered software pipeline.
//   - CPT=4 cells/thread/iter (pred 12 float4, targ 7 float4, both 16B-aligned)
//   - 512 blocks x 256 thr = whole grid resident (2 blocks/CU, 8 waves/CU)
//   - 4 iterations/thread, A/B reg buffers: issue loads(it+1) BEFORE compute(it)
//     -> compiler emits s_waitcnt vmcnt(19) (prefetch stays in flight), never 0
//   - sched_barrier(0) pins prefetch loads above the compute phase
//   - last iter: clamped loads (always valid), guarded accumulate
//   - per-wave shuffle reduce -> plain store; no LDS, no atomics

constexpr int S = 7;
constexpr int CELLS = 32768 * S * S;     // 1,605,632
constexpr int CPT = 4;                   // cells per thread per iteration
constexpr int TPB = 256;
constexpr int NBLK = 512;                // 2 blocks/CU exactly
constexpr int NTH = NBLK * TPB;          // 131,072 threads
constexpr int NWAVES = NTH / 64;         // 2048
constexpr float LAMBDA_COORD = 5.0f;
constexpr float LAMBDA_NOOBJ = 0.5f;
constexpr float INV_S = 1.0f / 7.0f;

__device__ __forceinline__ float cell_loss(const float* p, const float* t,
                                           float fcol, float frow) {
    float x0 = p[0], y0 = p[1], w0 = p[2], h0 = p[3], c0 = p[4];
    float x1 = p[5], y1 = p[6], w1 = p[7], h1 = p[8], c1 = p[9];
    float q0 = p[10], q1 = p[11];
    float tx = t[0], ty = t[1], tw = t[2], th = t[3], tp = t[4];
    float s0 = t[5], s1 = t[6];

    // target corners + area
    float tcx = (tx + fcol) * INV_S, tcy = (ty + frow) * INV_S;
    float tX1 = tcx - tw * 0.5f, tY1 = tcy - th * 0.5f;
    float tX2 = tcx + tw * 0.5f, tY2 = tcy + th * 0.5f;
    float ta = fabsf((tX2 - tX1) * (tY2 - tY1));

    // box 0
    float cx0 = (x0 + fcol) * INV_S, cy0 = (y0 + frow) * INV_S;
    float aX1 = cx0 - w0 * 0.5f, aY1 = cy0 - h0 * 0.5f;
    float aX2 = cx0 + w0 * 0.5f, aY2 = cy0 + h0 * 0.5f;
    float inter0 = fmaxf(fminf(aX2, tX2) - fmaxf(aX1, tX1), 0.0f) *
                   fmaxf(fminf(aY2, tY2) - fmaxf(aY1, tY1), 0.0f);
    float ar0 = fabsf((aX2 - aX1) * (aY2 - aY1));
    float u0 = ar0 + ta - inter0 + 1e-8f;      // > 0 always

    // box 1
    float cx1 = (x1 + fcol) * INV_S, cy1 = (y1 + frow) * INV_S;
    float bX1 = cx1 - w1 * 0.5f, bY1 = cy1 - h1 * 0.5f;
    float bX2 = cx1 + w1 * 0.5f, bY2 = cy1 + h1 * 0.5f;
    float inter1 = fmaxf(fminf(bX2, tX2) - fmaxf(bX1, tX1), 0.0f) *
                   fmaxf(fminf(bY2, tY2) - fmaxf(bY1, tY1), 0.0f);
    float ar1 = fabsf((bX2 - bX1) * (bY2 - bY1));
    float u1 = ar1 + ta - inter1 + 1e-8f;

    // argmax(iou): box1 iff iou1 > iou0  <=>  inter1*u0 > inter0*u1  (u > 0)
    bool sel1 = inter1 * u0 > inter0 * u1;
    float px = sel1 ? x1 : x0;
    float py = sel1 ? y1 : y0;
    float pw = sel1 ? w1 : w0;
    float ph = sel1 ? h1 : h0;
    float pp = sel1 ? c1 : c0;

    float obj = (tp > 0.0f) ? 1.0f : 0.0f;
    float noobj = 1.0f - obj;

    float dx = px - tx, dy = py - ty;
    float centre = dx * dx + dy * dy;

    float sgnw = (pw > 0.0f) ? 1.0f : ((pw < 0.0f) ? -1.0f : 0.0f);
    float sgnh = (ph > 0.0f) ? 1.0f : ((ph < 0.0f) ? -1.0f : 0.0f);
    float dw = sgnw * sqrtf(fabsf(pw) + 1e-6f) - sqrtf(tw);
    float dh = sgnh * sqrtf(fabsf(ph) + 1e-6f) - sqrtf(th);
    float dim = dw * dw + dh * dh;

    float dconf = pp - tp;
    float n0 = c0 - tp, n1 = c1 - tp;
    float dc0 = q0 - s0, dc1 = q1 - s1;

    return obj * (LAMBDA_COORD * (centre + dim) + dconf * dconf + dc0 * dc0 + dc1 * dc1)
         + noobj * LAMBDA_NOOBJ * (n0 * n0 + n1 * n1);
}

#define LOADP(buf, cellbase) { \
    const float4* _p = reinterpret_cast<const float4*>(pred + (size_t)(cellbase) * 12); \
    _Pragma("unroll") for (int k = 0; k < 12; ++k) (buf)[k] = _p[k]; }

#define LOADT(buf, cellbase) { \
    const float4* _t = reinterpret_cast<const float4*>(targ + (size_t)(cellbase) * 7); \
    _Pragma("unroll") for (int k = 0; k < 7; ++k) (buf)[k] = _t[k]; }

#define FENCE4(buf, n) { \
    _Pragma("unroll") for (int k = 0; k < (n); ++k) \
        asm volatile("" : "+v"((buf)[k].x), "+v"((buf)[k].y), "+v"((buf)[k].z), "+v"((buf)[k].w)); }

#define COMPUTE(pbuf, tbuf, cellbase) { \
    const float* _pf = reinterpret_cast<const float*>(pbuf); \
    const float* _tf = reinterpret_cast<const float*>(tbuf); \
    int _b = (cellbase); int _j = _b % S; int _i = (_b / S) % S; \
    _Pragma("unroll") for (int k = 0; k < CPT; ++k) { \
        acc += cell_loss(_pf + k * 12, _tf + k * 7, (float)_j, (float)_i); \
        if (++_j == S) { _j = 0; if (++_i == S) _i = 0; } } }

__global__ __launch_bounds__(TPB, 2)
void yolo_loss_kernel(const float* __restrict__ pred,
                      const float* __restrict__ targ,
                      double* __restrict__ ws) {
    const int tid0 = blockIdx.x * TPB + threadIdx.x;
    float acc = 0.0f;

    const int b0 = tid0 * CPT;                 // iter-0 cells
    const int b1 = (NTH + tid0) * CPT;         // iter-1
    const int b2 = (2 * NTH + tid0) * CPT;     // iter-2
    const int b3raw = (3 * NTH + tid0) * CPT;  // iter-3 (partial)
    const bool act3 = b3raw < CELLS;
    const int b3 = act3 ? b3raw : (CELLS - CPT);   // clamp -> always-valid load

    float4 pA[12], tA[7], pB[12], tB[7];

    // prologue: tile 0 into A
    LOADP(pA, b0); LOADT(tA, b0);

    // it 0: prefetch tile 1 -> B, compute A
    LOADP(pB, b1); LOADT(tB, b1);
    __builtin_amdgcn_sched_barrier(0);
    FENCE4(pA, 12); FENCE4(tA, 7);
    COMPUTE(pA, tA, b0);

    // it 1: prefetch tile 2 -> A, compute B
    LOADP(pA, b2); LOADT(tA, b2);
    __builtin_amdgcn_sched_barrier(0);
    FENCE4(pB, 12); FENCE4(tB, 7);
    COMPUTE(pB, tB, b1);

    // it 2: prefetch tile 3 (clamped) -> B, compute A
    LOADP(pB, b3); LOADT(tB, b3);
    __builtin_amdgcn_sched_barrier(0);
    FENCE4(pA, 12); FENCE4(tA, 7);
    COMPUTE(pA, tA, b2);

    // it 3: compute B (guarded; inactive waves skip whole branch)
    FENCE4(pB, 12); FENCE4(tB, 7);
    if (act3) { COMPUTE(pB, tB, b3raw); }

    // per-wave reduction in double -> one plain 8B store per wave
    double v = (double)acc;
    #pragma unroll
    for (int off = 32; off > 0; off >>= 1)
        v += __shfl_down(v, off, 64);

    if ((threadIdx.x & 63) == 0)
        ws[tid0 >> 6] = v;
}

__global__ __launch_bounds__(256)
void reduce_kernel(const double* __restrict__ ws, float* __restrict__ out) {
    int t = threadIdx.x;
    double s = 0.0;
    for (int idx = t; idx < NWAVES; idx += 256) s += ws[idx];

    #pragma unroll
    for (int off = 32; off > 0; off >>= 1)
        s += __shfl_down(s, off, 64);

    __shared__ double sm[4];
    int lane = t & 63, wid = t >> 6;
    if (lane == 0) sm[wid] = s;
    __syncthreads();
    if (t == 0) out[0] = (float)(sm[0] + sm[1] + sm[2] + sm[3]);
}

extern "C" void kernel_launch(void* const* d_in, const int* in_sizes, int n_in,
                              void* d_out, int out_size, void* d_ws, size_t ws_size,
                              hipStream_t stream) {
    const float* pred = (const float*)d_in[0];
    const float* targ = (const float*)d_in[1];
    float* out = (float*)d_out;
    double* ws = (double*)d_ws;

    yolo_loss_kernel<<<NBLK, TPB, 0, stream>>>(pred, targ, ws);
    reduce_kernel<<<1, 256, 0, stream>>>(ws, out);
}